// Round 3
// baseline (575.552 us; speedup 1.0000x reference)
//
#include <hip/hip_runtime.h>
#include <math.h>

#define BB 4
#define CCH 128
#define HH 384
#define WW 384

constexpr int TILE_X = 64;
constexpr int TILE_Y = 12;          // 768 blocks = exactly 3/CU
constexpr int CC = 4;               // channels per staged chunk
constexpr int NCHUNK = CCH / CC;    // 32
constexpr int BROWS = 6;            // rows staged per compute wave (4 compute + 2 halo)
constexpr int PROWS = 14;           // norm/label tile rows (y0 .. y0+13)
constexpr int STR  = 72;            // floats per stage row; col l <-> gx = x0-4+l
constexpr int GR   = 18;            // float4 groups per row
constexpr int WVEC = CC * BROWS * GR; // 432 float4 per wave-chunk
constexpr int WLD  = 7;             // ceil(432/64) loads per lane per chunk
constexpr int WBUFV = WLD * 64 * 4; // 1792 floats (7168 B) per buffer (pad for ragged tail)
constexpr int NSTR = 76;            // norm tile stride (16B-aligned rows)
#define EPSQ 1e-8f

// 12 forward shifts: (0,1),(0,2),(1,-2..2),(2,-2..2). Each unordered pair {p,q}
// visited once with weight sel(p)+sel(q) == reference's 24 directed shifts.
// Clamped staging addresses only affect don't-care values (weight-0 pairs).
//
// BARRIER-FREE hot loop: each compute wave w (0..2) owns rows y0+4w..y0+4w+3
// and stages its own 6-row band (rows 4w..4w+5) into wave-private
// double-buffered LDS via global_load_lds. No cross-wave LDS sharing in the
// chunk loop -> no s_barrier for 32 chunks; each wave self-paces on
// s_waitcnt vmcnt(7) (chunk k landed, chunk k+1's 7 loads stay in flight).
// Reuse safety (2 buffers/wave): chunk k+2 is issued only after chunk k's
// ds_reads were consumed by FMAs (lgkm drained by data use); the LDS unit
// services earlier-queued reads before the async return-write lands.
// sched_barrier(0) pins: [vmcnt wait] < [ds_reads] < [issue k+2].
// Wave 3 computes rows 12/13 halo norms straight from global (no LDS).

__global__ __launch_bounds__(256, 3)
void ctx_main(const float* __restrict__ er, const int* __restrict__ seg,
              const int* __restrict__ gt, float* __restrict__ Ssum,
              int* __restrict__ cntArr, int* __restrict__ bndArr)
{
    __shared__ __align__(16) float wbuf[3 * 2 * WBUFV];   // 43008 B (3 waves x 2 bufs)
    __shared__ __align__(16) float normArr[PROWS * NSTR]; //  4256 B
    // total 47264 B -> 3 blocks/CU with margin

    const int tx   = threadIdx.x;           // 0..15 (x groups of 4 px)
    const int ty   = threadIdx.y;           // 0..15
    const int tid  = ty * 16 + tx;
    const int lane = tid & 63;
    const int w    = tid >> 6;              // wave 0..3
    const int tyl  = (lane >> 4);           // 0..3 row within wave band (== ty & 3)
    const int x0   = blockIdx.x * TILE_X;
    const int y0   = blockIdx.y * TILE_Y;
    const int b    = blockIdx.z;

    const float* erB = er + (size_t)b * CCH * HH * WW;

    float acc[12][4];
    #pragma unroll
    for (int s = 0; s < 12; ++s)
        #pragma unroll
        for (int i = 0; i < 4; ++i) acc[s][i] = 0.f;
    float nrm[4] = {0.f, 0.f, 0.f, 0.f};
    float haloN = 0.f;
    float n2w3[4] = {0.f, 0.f, 0.f, 0.f};

    // side-halo norm columns for waves 0-2 (lanes 0..15): rows 4w..4w+3, cols {2,3,68,69}
    const int hrow = (lane >> 2) & 3;
    const int hj   = lane & 3;
    const int hcol = (hj < 2) ? (2 + hj) : (66 + hj);   // 2,3,68,69

    // wave-3 pixel assignment (rows y0+12, y0+13)
    const int l3    = lane;
    const bool act3 = (l3 < 36);
    const int row2  = l3 / 18;
    const int g3    = l3 - row2 * 18;

    if (w < 3) {
        // ---- staging source offsets (within a CC-channel slab), computed once ----
        int srcOff[WLD];
        #pragma unroll
        for (int j = 0; j < WLD; ++j) {
            int id = lane + 64 * j; if (id > WVEC - 1) id = WVEC - 1;
            int c   = id / (BROWS * GR);
            int rem = id - c * (BROWS * GR);
            int r   = rem / GR;
            int g   = rem - r * GR;
            int gy  = y0 + 4 * w + r; if (gy > HH - 1) gy = HH - 1;
            int gx  = x0 - 4 + 4 * g;
            gx = min(max(gx, 0), WW - 4);
            srcOff[j] = (c * HH + gy) * WW + gx;
        }

        float* bA = &wbuf[(w * 2 + 0) * WBUFV];
        float* bB = &wbuf[(w * 2 + 1) * WBUFV];

        auto issue = [&](int chunk, float* dst) {
            const float* erC = erB + (size_t)chunk * CC * HH * WW;
            #pragma unroll
            for (int j = 0; j < WLD; ++j) {
                __builtin_amdgcn_global_load_lds(
                    (const __attribute__((address_space(1))) void*)(erC + srcOff[j]),
                    (__attribute__((address_space(3))) void*)(dst + 4 * (lane + 64 * j)),
                    16, 0, 0);
            }
        };

        issue(0, bA);
        issue(1, bB);

        for (int k = 0; k < NCHUNK; ++k) {
            float* cur = (k & 1) ? bB : bA;
            if (k < NCHUNK - 1)
                asm volatile("s_waitcnt vmcnt(7)" ::: "memory");
            else
                asm volatile("s_waitcnt vmcnt(0)" ::: "memory");
            __builtin_amdgcn_sched_barrier(0);

            // ---- accumulate dots (12 fwd shifts) + own norms; aligned b128 reads ----
            #pragma unroll
            for (int c = 0; c < CC; ++c) {
                const float* rp = &cur[(c * BROWS + tyl) * STR + 4 * tx];
                float L0[12], L1[12], L2[12];
                #pragma unroll
                for (int jj = 0; jj < 3; ++jj) {
                    *(float4*)&L0[4 * jj] = *(const float4*)(rp + 4 * jj);
                    *(float4*)&L1[4 * jj] = *(const float4*)(rp + STR + 4 * jj);
                    *(float4*)&L2[4 * jj] = *(const float4*)(rp + 2 * STR + 4 * jj);
                }
                #pragma unroll
                for (int i = 0; i < 4; ++i) {
                    float f = L0[4 + i];
                    nrm[i]    = fmaf(f, f,         nrm[i]);
                    acc[0][i] = fmaf(f, L0[5 + i], acc[0][i]);   // (0,+1)
                    acc[1][i] = fmaf(f, L0[6 + i], acc[1][i]);   // (0,+2)
                    #pragma unroll
                    for (int d = 0; d < 5; ++d) {                // dx = d-2
                        acc[2 + d][i] = fmaf(f, L1[2 + i + d], acc[2 + d][i]); // dy=1
                        acc[7 + d][i] = fmaf(f, L2[2 + i + d], acc[7 + d][i]); // dy=2
                    }
                }
            }
            // ---- side-halo column norm partials (own band rows 0..3) ----
            if (lane < 16) {
                #pragma unroll
                for (int c = 0; c < CC; ++c) {
                    float v = cur[(c * BROWS + hrow) * STR + hcol];
                    haloN = fmaf(v, v, haloN);
                }
            }

            __builtin_amdgcn_sched_barrier(0);
            if (k + 2 < NCHUNK) issue(k + 2, cur);   // overwrite just-consumed buffer
        }
        __builtin_amdgcn_sched_barrier(0);
    } else {
        // ---- wave 3: norms of rows y0+12, y0+13 (all 72 staged cols), global->reg ----
        if (act3) {
            int gy = y0 + 12 + row2; if (gy > HH - 1) gy = HH - 1;
            int gx = x0 - 4 + 4 * g3; gx = min(max(gx, 0), WW - 4);
            const size_t base = (size_t)gy * WW + gx;
            #pragma unroll 8
            for (int ch = 0; ch < CCH; ++ch) {
                float4 v = *(const float4*)(erB + (size_t)ch * HH * WW + base);
                n2w3[0] = fmaf(v.x, v.x, n2w3[0]);
                n2w3[1] = fmaf(v.y, v.y, n2w3[1]);
                n2w3[2] = fmaf(v.z, v.z, n2w3[2]);
                n2w3[3] = fmaf(v.w, v.w, n2w3[3]);
            }
        }
    }

    __syncthreads();   // #1: all wbuf reads done; buffers reusable

    // ---- build packed label/mask tile (reuse wbuf) ----
    int* pkT = (int*)wbuf;
    for (int it = tid; it < PROWS * STR; it += 256) {
        int r = it / STR, a = it - r * STR;
        int gy = y0 + r;
        int gx = x0 - 4 + a;
        int pk = 0;
        if (gy < HH && gx >= 0 && gx < WW) {
            int g   = gt[((size_t)b * HH + gy) * WW + gx];
            int gb  = (g == 255) ? 0 : g;
            int s0v = seg[(((size_t)b * 2 + 0) * HH + gy) * WW + gx];
            int s1v = seg[(((size_t)b * 2 + 1) * HH + gy) * WW + gx];
            int s1c = (s1v == 255) ? 0 : s1v;
            bool bnd   = (gb * s1c) > 0;
            bool inter = (gy >= 2 && gy <= HH - 3 && gx >= 2 && gx <= WW - 3);
            pk = (bnd ? 1 : 0) | ((bnd && inter) ? 2 : 0)
               | ((s0v & 255) << 8) | ((s1v & 255) << 16);
        }
        pkT[it] = pk;
    }
    // ---- norm writes (disjoint cells) ----
    if (w < 3) {
        #pragma unroll
        for (int i = 0; i < 4; ++i)
            normArr[ty * NSTR + 4 * tx + 4 + i] = sqrtf(nrm[i]);
        if (lane < 16)
            normArr[(4 * w + hrow) * NSTR + hcol] = sqrtf(haloN);
    } else if (act3) {
        #pragma unroll
        for (int i = 0; i < 4; ++i)
            normArr[(12 + row2) * NSTR + 4 * g3 + i] = sqrtf(n2w3[i]);
    }
    __syncthreads();   // #2: pkT + normArr visible

    // ---- pair epilogue (12-wide windows; own px at indices 4..7) ----
    float Sth = 0.f; int cth = 0, bth = 0;
    if (ty < TILE_Y) {
        const float* nr = &normArr[ty * NSTR + 4 * tx];
        const int*   pr = &pkT[ty * STR + 4 * tx];
        float n0[12], n1[12], n2[12];
        int   p0[12], p1[12], p2[12];
        #pragma unroll
        for (int jj = 0; jj < 3; ++jj) {
            *(float4*)&n0[4 * jj] = *(const float4*)(nr + 4 * jj);
            *(float4*)&n1[4 * jj] = *(const float4*)(nr + NSTR + 4 * jj);
            *(float4*)&n2[4 * jj] = *(const float4*)(nr + 2 * NSTR + 4 * jj);
            *(int4*)&p0[4 * jj] = *(const int4*)(pr + 4 * jj);
            *(int4*)&p1[4 * jj] = *(const int4*)(pr + STR + 4 * jj);
            *(int4*)&p2[4 * jj] = *(const int4*)(pr + 2 * STR + 4 * jj);
        }

        #pragma unroll
        for (int i = 0; i < 4; ++i) {
            int pkP  = p0[4 + i];
            int selP = (pkP >> 1) & 1;
            cth += selP;
            bth += pkP & 1;
            float nP = fmaxf(n0[4 + i], EPSQ);
            auto doPair = [&](float dot, int pkQ, float nQv) {
                int wgt = selP + ((pkQ >> 1) & 1);
                if (wgt) {
                    float lab = (float)(((pkP >> 8) & 255) * ((pkQ >> 8) & 255)
                                      + ((pkP >> 16) & 255) * ((pkQ >> 16) & 255));
                    float cs = dot / (nP * fmaxf(nQv, EPSQ));
                    float d  = cs - lab;
                    Sth = fmaf((float)wgt * d, d, Sth);
                }
            };
            doPair(acc[0][i], p0[5 + i], n0[5 + i]);
            doPair(acc[1][i], p0[6 + i], n0[6 + i]);
            #pragma unroll
            for (int d2 = 0; d2 < 5; ++d2) {
                doPair(acc[2 + d2][i], p1[2 + i + d2], n1[2 + i + d2]);
                doPair(acc[7 + d2][i], p2[2 + i + d2], n2[2 + i + d2]);
            }
        }
    }

    // ---- reduce + atomics (one per wave; wave 3 contributes zeros) ----
    #pragma unroll
    for (int off = 32; off > 0; off >>= 1) {
        Sth += __shfl_down(Sth, off);
        cth += __shfl_down(cth, off);
        bth += __shfl_down(bth, off);
    }
    if ((tid & 63) == 0) {
        atomicAdd(&Ssum[b], Sth);
        atomicAdd(&cntArr[b], cth);
        atomicAdd(&bndArr[b], bth);
    }
}

__global__ void ctx_init(float* S, int* cnt, int* bnd) {
    int t = threadIdx.x;
    if (t < BB) { S[t] = 0.f; cnt[t] = 0; bnd[t] = 0; }
}

__global__ void ctx_finalize(const float* __restrict__ S, const int* __restrict__ cnt,
                             const int* __restrict__ bnd, float* __restrict__ out) {
    if (threadIdx.x == 0 && blockIdx.x == 0) {
        float tot = 0.f, nv = 0.f;
        for (int b = 0; b < BB; ++b) {
            if (bnd[b] >= 1) {
                float c = fmaxf((float)cnt[b], 1.f);
                tot += S[b] / (24.f * c);
                nv  += 1.f;
            }
        }
        tot = tot / fmaxf(nv, 1.f);
        if (isnan(tot)) tot = 0.f;
        out[0] = tot;
    }
}

extern "C" void kernel_launch(void* const* d_in, const int* in_sizes, int n_in,
                              void* d_out, int out_size, void* d_ws, size_t ws_size,
                              hipStream_t stream) {
    const float* er = (const float*)d_in[0];
    const int* seg  = (const int*)d_in[1];
    const int* gt   = (const int*)d_in[2];
    float* out = (float*)d_out;

    float* S   = (float*)d_ws;
    int*   cnt = (int*)d_ws + BB;
    int*   bnd = (int*)d_ws + 2 * BB;

    ctx_init<<<1, 64, 0, stream>>>(S, cnt, bnd);
    dim3 grid(WW / TILE_X, HH / TILE_Y, BB);
    dim3 block(16, 16);
    ctx_main<<<grid, block, 0, stream>>>(er, seg, gt, S, cnt, bnd);
    ctx_finalize<<<1, 64, 0, stream>>>(S, cnt, bnd, out);
}

// Round 4
// 510.459 us; speedup vs baseline: 1.1275x; 1.1275x over previous
//
#include <hip/hip_runtime.h>
#include <math.h>

#define BB 4
#define CCH 128
#define HH 384
#define WW 384

constexpr int TILE_Y = 6;            // 64 y-tiles x 4 batches = 256 blocks = 1/CU exactly
constexpr int CC = 2;                // channels per staged chunk
constexpr int NCHUNK = CCH / CC;     // 64
constexpr int SROWS = 8;             // staged rows y0..y0+7 (6 compute + 2 fwd halo)
constexpr int SSLOT = 98;            // float4 slots/row: 96 real + 1 clamp pad each side
constexpr int SSTR  = SSLOT * 4;     // 392 floats per staged row; pcol p <-> gx = p-4
constexpr int CSLOT = CC * SROWS * SSLOT;  // 1568 float4 per chunk
constexpr int NTHR  = 576;           // 96 x 6 = 9 waves
constexpr int NLD   = 3;             // ceil(1568/576) loads/thread/chunk (tail clamped)
constexpr int BUFV  = NLD * NTHR * 4; // 6912 floats/buffer (27648 B, incl clamp-tail pad)
#define EPSQ 1e-8f

// 12 forward shifts: (0,1),(0,2),(1,-2..2),(2,-2..2); each unordered pair {p,q}
// once with weight sel(p)+sel(q) == reference's 24 directed shifts. Clamp pads
// only feed weight-0 pairs (sel needs the 2-px interior margin).
//
// FULL-ROW tiles: staged bytes are CONTIGUOUS 12288-B runs per channel plane
// (8 adjacent rows x 1536 B) -> DRAM row-buffer friendly streaming, no x-halo.
// Quad-buffered global_load_lds, prefetch depth 3, ONE fused
// {s_waitcnt vmcnt(6) lgkmcnt(0); s_barrier} per chunk: chunk k's 3 loads
// drained, k+1/k+2's 6 stay in flight ACROSS the barrier. issue(k+3) targets
// the buffer last read at chunk k-1 (all readers passed this barrier) -> no race.
// Dest slots are linear (base + 16*id); src(id) pre-applies the row pad/clamp.

__global__ __launch_bounds__(576, 2)
void ctx_main(const float* __restrict__ er, const int* __restrict__ seg,
              const int* __restrict__ gt, float* __restrict__ Ssum,
              int* __restrict__ cntArr, int* __restrict__ bndArr)
{
    __shared__ __align__(16) float stage[4 * BUFV];        // 110592 B
    __shared__ __align__(16) float normArr[SROWS * SSTR];  //  12544 B
    // total 123136 B -> 1 block/CU

    const int tx  = threadIdx.x;      // 0..95 (x groups of 4 px)
    const int ty  = threadIdx.y;      // 0..5  (compute rows)
    const int tid = ty * 96 + tx;
    const int y0  = blockIdx.x * TILE_Y;
    const int b   = blockIdx.y;

    const float* erB = er + (size_t)b * CCH * HH * WW;

    // ---- staging source offsets (within a CC-channel slab), computed once ----
    int srcOff[NLD];
    #pragma unroll
    for (int j = 0; j < NLD; ++j) {
        int id = tid + NTHR * j; if (id > CSLOT - 1) id = CSLOT - 1;
        int c   = id / (SROWS * SSLOT);
        int rem = id - c * (SROWS * SSLOT);
        int r   = rem / SSLOT;
        int s   = rem - r * SSLOT;
        int gx4 = s - 1; gx4 = min(max(gx4, 0), 95);
        int gy  = y0 + r; if (gy > HH - 1) gy = HH - 1;
        srcOff[j] = (c * HH + gy) * WW + 4 * gx4;
    }

    auto issue = [&](int chunk, float* dst) {
        const float* erC = erB + (size_t)chunk * CC * HH * WW;
        #pragma unroll
        for (int j = 0; j < NLD; ++j) {
            __builtin_amdgcn_global_load_lds(
                (const __attribute__((address_space(1))) void*)(erC + srcOff[j]),
                (__attribute__((address_space(3))) void*)(dst + 4 * (tid + NTHR * j)),
                16, 0, 0);
        }
    };

    float acc[12][4];
    #pragma unroll
    for (int s = 0; s < 12; ++s)
        #pragma unroll
        for (int i = 0; i < 4; ++i) acc[s][i] = 0.f;
    float nrm[4] = {0.f, 0.f, 0.f, 0.f};
    float nh[4]  = {0.f, 0.f, 0.f, 0.f};   // halo rows 6,7 norms (ty<2 threads)

    float* bA = stage;                // chunk k   (current)
    float* bB = stage + BUFV;         // chunk k+1 (in flight)
    float* bC = stage + 2 * BUFV;     // chunk k+2 (in flight)
    float* bD = stage + 3 * BUFV;     // free (chunk k-1's buffer) -> issue k+3

    issue(0, bA);
    issue(1, bB);
    issue(2, bC);

    for (int k = 0; k < NCHUNK; ++k) {
        float* cur = bA;
        // fused wait+barrier: chunk k landed; k+1,k+2 (6 loads) stay in flight
        if (k <= NCHUNK - 3)
            asm volatile("s_waitcnt vmcnt(6) lgkmcnt(0)\n\ts_barrier" ::: "memory");
        else if (k == NCHUNK - 2)
            asm volatile("s_waitcnt vmcnt(3) lgkmcnt(0)\n\ts_barrier" ::: "memory");
        else
            asm volatile("s_waitcnt vmcnt(0) lgkmcnt(0)\n\ts_barrier" ::: "memory");
        __builtin_amdgcn_sched_barrier(0);   // nothing hoists above the barrier
        if (k + 3 < NCHUNK) issue(k + 3, bD);

        // ---- accumulate dots (12 fwd shifts) + own norms; aligned b128 reads ----
        #pragma unroll
        for (int c = 0; c < CC; ++c) {
            const float* rp = &cur[(c * SROWS + ty) * SSTR + 4 * tx];
            float L0[12], L1[12], L2[12];
            #pragma unroll
            for (int jj = 0; jj < 3; ++jj) {
                *(float4*)&L0[4 * jj] = *(const float4*)(rp + 4 * jj);
                *(float4*)&L1[4 * jj] = *(const float4*)(rp + SSTR + 4 * jj);
                *(float4*)&L2[4 * jj] = *(const float4*)(rp + 2 * SSTR + 4 * jj);
            }
            #pragma unroll
            for (int i = 0; i < 4; ++i) {
                float f = L0[4 + i];
                nrm[i]    = fmaf(f, f,         nrm[i]);
                acc[0][i] = fmaf(f, L0[5 + i], acc[0][i]);   // (0,+1)
                acc[1][i] = fmaf(f, L0[6 + i], acc[1][i]);   // (0,+2)
                #pragma unroll
                for (int d = 0; d < 5; ++d) {                // dx = d-2
                    acc[2 + d][i] = fmaf(f, L1[2 + i + d], acc[2 + d][i]); // dy=1
                    acc[7 + d][i] = fmaf(f, L2[2 + i + d], acc[7 + d][i]); // dy=2
                }
            }
            // ---- halo rows 6,7 norm partials (waves 0-2: tid<192, wave-uniform) ----
            if (ty < 2) {
                float4 hv = *(const float4*)&cur[(c * SROWS + 6 + ty) * SSTR + 4 * tx + 4];
                nh[0] = fmaf(hv.x, hv.x, nh[0]);
                nh[1] = fmaf(hv.y, hv.y, nh[1]);
                nh[2] = fmaf(hv.z, hv.z, nh[2]);
                nh[3] = fmaf(hv.w, hv.w, nh[3]);
            }
        }

        // rotate buffers
        float* t = bA; bA = bB; bB = bC; bC = bD; bD = t;
    }

    // ---- build packed label/mask tile (reuse stage buf 0; its DMA/readers done) ----
    int* pkT = (int*)stage;
    for (int it = tid; it < SROWS * SSTR; it += NTHR) {
        int r = it / SSTR, p = it - r * SSTR;
        int gy = y0 + r;
        int gx = p - 4;
        int pk = 0;
        if (gy < HH && gx >= 0 && gx < WW) {
            int g   = gt[((size_t)b * HH + gy) * WW + gx];
            int gb  = (g == 255) ? 0 : g;
            int s0v = seg[(((size_t)b * 2 + 0) * HH + gy) * WW + gx];
            int s1v = seg[(((size_t)b * 2 + 1) * HH + gy) * WW + gx];
            int s1c = (s1v == 255) ? 0 : s1v;
            bool bnd   = (gb * s1c) > 0;
            bool inter = (gy >= 2 && gy <= HH - 3 && gx >= 2 && gx <= WW - 3);
            pk = (bnd ? 1 : 0) | ((bnd && inter) ? 2 : 0)
               | ((s0v & 255) << 8) | ((s1v & 255) << 16);
        }
        pkT[it] = pk;
    }
    // ---- norm writes (disjoint cells) ----
    #pragma unroll
    for (int i = 0; i < 4; ++i)
        normArr[ty * SSTR + 4 * tx + 4 + i] = sqrtf(nrm[i]);
    if (ty < 2) {
        #pragma unroll
        for (int i = 0; i < 4; ++i)
            normArr[(6 + ty) * SSTR + 4 * tx + 4 + i] = sqrtf(nh[i]);
    }
    __syncthreads();   // pkT + normArr visible

    // ---- pair epilogue (12-wide windows; own px at indices 4..7) ----
    float Sth = 0.f; int cth = 0, bth = 0;
    {
        const float* nr = &normArr[ty * SSTR + 4 * tx];
        const int*   pr = &pkT[ty * SSTR + 4 * tx];
        float n0[12], n1[12], n2[12];
        int   p0[12], p1[12], p2[12];
        #pragma unroll
        for (int jj = 0; jj < 3; ++jj) {
            *(float4*)&n0[4 * jj] = *(const float4*)(nr + 4 * jj);
            *(float4*)&n1[4 * jj] = *(const float4*)(nr + SSTR + 4 * jj);
            *(float4*)&n2[4 * jj] = *(const float4*)(nr + 2 * SSTR + 4 * jj);
            *(int4*)&p0[4 * jj] = *(const int4*)(pr + 4 * jj);
            *(int4*)&p1[4 * jj] = *(const int4*)(pr + SSTR + 4 * jj);
            *(int4*)&p2[4 * jj] = *(const int4*)(pr + 2 * SSTR + 4 * jj);
        }

        #pragma unroll
        for (int i = 0; i < 4; ++i) {
            int pkP  = p0[4 + i];
            int selP = (pkP >> 1) & 1;
            cth += selP;
            bth += pkP & 1;
            float nP = fmaxf(n0[4 + i], EPSQ);
            auto doPair = [&](float dot, int pkQ, float nQv) {
                int wgt = selP + ((pkQ >> 1) & 1);
                if (wgt) {
                    float lab = (float)(((pkP >> 8) & 255) * ((pkQ >> 8) & 255)
                                      + ((pkP >> 16) & 255) * ((pkQ >> 16) & 255));
                    float cs = dot / (nP * fmaxf(nQv, EPSQ));
                    float d  = cs - lab;
                    Sth = fmaf((float)wgt * d, d, Sth);
                }
            };
            doPair(acc[0][i], p0[5 + i], n0[5 + i]);
            doPair(acc[1][i], p0[6 + i], n0[6 + i]);
            #pragma unroll
            for (int d2 = 0; d2 < 5; ++d2) {
                doPair(acc[2 + d2][i], p1[2 + i + d2], n1[2 + i + d2]);
                doPair(acc[7 + d2][i], p2[2 + i + d2], n2[2 + i + d2]);
            }
        }
    }

    // ---- reduce + atomics (one per wave) ----
    #pragma unroll
    for (int off = 32; off > 0; off >>= 1) {
        Sth += __shfl_down(Sth, off);
        cth += __shfl_down(cth, off);
        bth += __shfl_down(bth, off);
    }
    if ((tid & 63) == 0) {
        atomicAdd(&Ssum[b], Sth);
        atomicAdd(&cntArr[b], cth);
        atomicAdd(&bndArr[b], bth);
    }
}

__global__ void ctx_init(float* S, int* cnt, int* bnd) {
    int t = threadIdx.x;
    if (t < BB) { S[t] = 0.f; cnt[t] = 0; bnd[t] = 0; }
}

__global__ void ctx_finalize(const float* __restrict__ S, const int* __restrict__ cnt,
                             const int* __restrict__ bnd, float* __restrict__ out) {
    if (threadIdx.x == 0 && blockIdx.x == 0) {
        float tot = 0.f, nv = 0.f;
        for (int b = 0; b < BB; ++b) {
            if (bnd[b] >= 1) {
                float c = fmaxf((float)cnt[b], 1.f);
                tot += S[b] / (24.f * c);
                nv  += 1.f;
            }
        }
        tot = tot / fmaxf(nv, 1.f);
        if (isnan(tot)) tot = 0.f;
        out[0] = tot;
    }
}

extern "C" void kernel_launch(void* const* d_in, const int* in_sizes, int n_in,
                              void* d_out, int out_size, void* d_ws, size_t ws_size,
                              hipStream_t stream) {
    const float* er = (const float*)d_in[0];
    const int* seg  = (const int*)d_in[1];
    const int* gt   = (const int*)d_in[2];
    float* out = (float*)d_out;

    float* S   = (float*)d_ws;
    int*   cnt = (int*)d_ws + BB;
    int*   bnd = (int*)d_ws + 2 * BB;

    ctx_init<<<1, 64, 0, stream>>>(S, cnt, bnd);
    dim3 grid(HH / TILE_Y, BB);
    dim3 block(96, 6);
    ctx_main<<<grid, block, 0, stream>>>(er, seg, gt, S, cnt, bnd);
    ctx_finalize<<<1, 64, 0, stream>>>(S, cnt, bnd, out);
}